// Round 2
// baseline (2264.736 us; speedup 1.0000x reference)
//
#include <hip/hip_runtime.h>
#include <math.h>

// LSTM B=256, T=2048, D=H=64, OUT=8, fp32.
// Round-8: producer/consumer wave split with BARRIER-ONLY sync (round-7's
// lock-free spin handshake is the prime suspect for the container hang;
// replaced by a uniform __syncthreads per 16-step chunk -> provably
// deadlock-free double-buffer).
//  - Producer wave (wave 1): W_ih (256 VGPRs) in regs, streams x via
//    global_load_lds (16B), computes xg_t = scaled(W_ih x_t + b) for chunk
//    cc+1 into ring[(cc+1)&1] while consumer drains ring[cc&1].
//  - Consumer wave (wave 0): W_hh (256 VGPRs) in regs, walks the recurrence
//    ALONE: no per-step barrier, no cross-wave partial reduce. Per step:
//    h broadcast (1 ds_write + 16 same-addr ds_read_b128, conflict-free),
//    128 v_pk_fma_f32, hsum, pre-scaled-logit activations (exp2+rcp).
//  - One barrier per chunk (~3 cy/step amortized). Implicit vmcnt(0) drain
//    at each barrier closes the global_load_lds -> ds_read staging dep
//    (loads issued a full chunk ahead, ~5000 cy of cover).

#define Hh 64
#define Tt 2048
#define Bb 256
#define OUTN 8
#define CH 16                 // steps per chunk (barrier granularity)
#define NCHUNKS (Tt / CH)     // 128

typedef float floatx4 __attribute__((ext_vector_type(4)));
typedef float floatx2 __attribute__((ext_vector_type(2)));

__device__ __forceinline__ float hsum4(floatx4 a) {
    floatx2 t = a.lo + a.hi;          // v_pk_add_f32
    return t.x + t.y;
}

// sigma(z) given the PRE-SCALED logit zp = -log2e * z
__device__ __forceinline__ float sigm2(float zp) {
    return __builtin_amdgcn_rcpf(1.0f + __builtin_amdgcn_exp2f(zp));
}

__global__ __launch_bounds__(128, 1)
void lstm_pc_kernel(const float* __restrict__ x,
                    const float* __restrict__ w_ih,
                    const float* __restrict__ w_hh,
                    const float* __restrict__ b_ih,
                    const float* __restrict__ b_hh,
                    const float* __restrict__ fc_w,
                    const float* __restrict__ fc_b,
                    float* __restrict__ out)
{
    __shared__ __align__(16) float ring[2][CH][Hh][4];  // 32 KB: xg double-buffer
    __shared__ __align__(16) float xst[2][CH][Hh];      // 8 KB: x staging dbuf
    __shared__ __align__(16) float h_s[Hh];             // consumer's h broadcast

    const int tid  = threadIdx.x;
    const int b    = blockIdx.x;
    const int wave = tid >> 6;     // 1 = producer, 0 = consumer
    const int lane = tid & 63;
    const float* xb = x + (size_t)b * Tt * Hh;

    const float SC1 = -1.44269504088896340736f;   // -log2(e)
    const float SC2 = -2.88539008177792681472f;   // -2*log2(e)

    // ---- per-wave weight block: producer=W_ih, consumer=W_hh (scaled) ----
    floatx4 w[4][16];                             // 256 VGPRs, pinned
    {
        const float* wp = (wave == 1) ? w_ih : w_hh;
        #pragma unroll
        for (int g = 0; g < 4; ++g) {
            const float sc = (g == 2) ? SC2 : SC1;
            const floatx4* p = (const floatx4*)(wp + (size_t)((g << 6) + lane) * Hh);
            #pragma unroll
            for (int q = 0; q < 16; ++q) w[g][q] = p[q] * sc;
        }
        #pragma unroll
        for (int g = 0; g < 4; ++g)
            #pragma unroll
            for (int q = 0; q < 16; ++q)
                asm volatile("" : "+v"(w[g][q]));
    }

    floatx4 bias4;                                // used by producer only
    bias4.x = (b_ih[lane]       + b_hh[lane])       * SC1;   // i
    bias4.y = (b_ih[64 + lane]  + b_hh[64 + lane])  * SC1;   // f
    bias4.z = (b_ih[128 + lane] + b_hh[128 + lane]) * SC2;   // g (tanh)
    bias4.w = (b_ih[192 + lane] + b_hh[192 + lane]) * SC1;   // o

    // stage chunk -> xst[xbuf] (4 KB = 4 x 1KB wave-wide calls)
    auto stage_chunk = [&](int xbuf, int chunk) {
        const float* src = xb + (size_t)chunk * CH * Hh;
        float* dst = &xst[xbuf][0][0];
        #pragma unroll
        for (int p4 = 0; p4 < 4; ++p4)
            __builtin_amdgcn_global_load_lds(
                (const __attribute__((address_space(1))) void*)(src + p4 * 256 + lane * 4),
                (__attribute__((address_space(3))) void*)(dst + p4 * 256 + lane * 4),
                16, 0, 0);
    };

    // xg for one chunk: ring[rbuf][s][lane] = scaled(W_ih x_s + b)
    auto produce_chunk = [&](int rbuf, const float* xc) {
        for (int s = 0; s < CH; ++s) {
            const floatx4* xs = (const floatx4*)(xc + s * Hh);  // broadcast reads
            floatx4 a0, a1, a2, a3;
            {
                floatx4 v = xs[0];
                a0 = w[0][0] * v; a1 = w[1][0] * v;
                a2 = w[2][0] * v; a3 = w[3][0] * v;
            }
            #pragma unroll
            for (int q = 1; q < 16; ++q) {
                floatx4 v = xs[q];
                a0 = __builtin_elementwise_fma(w[0][q], v, a0);
                a1 = __builtin_elementwise_fma(w[1][q], v, a1);
                a2 = __builtin_elementwise_fma(w[2][q], v, a2);
                a3 = __builtin_elementwise_fma(w[3][q], v, a3);
            }
            floatx4 xg;
            xg.x = hsum4(a0); xg.y = hsum4(a1);
            xg.z = hsum4(a2); xg.w = hsum4(a3);
            xg += bias4;
            *(floatx4*)&ring[rbuf][s][lane][0] = xg;
        }
    };

    // ---- prologue: producer readies ring[0]; consumer zeroes h ----
    if (wave == 1) {
        stage_chunk(0, 0);
        stage_chunk(1, 1);
        asm volatile("s_waitcnt vmcnt(4)" ::: "memory");   // chunk 0 arrived
        __builtin_amdgcn_sched_barrier(0);
        produce_chunk(0, &xst[0][0][0]);
    } else {
        h_s[lane] = 0.0f;
    }

    float c = 0.0f;

    for (int cc = 0; cc < NCHUNKS; ++cc) {
        __syncthreads();   // ring[cc&1] ready; prior reads of ring[(cc+1)&1] retired

        if (wave == 1) {
            // stage chunk cc+2 into the xst buffer freed last iteration;
            // arrival is guaranteed by the next barrier's implicit vmcnt drain
            if (cc + 2 < NCHUNKS) stage_chunk(cc & 1, cc + 2);
            // chunk cc+1's x arrived before this iteration's barrier
            if (cc + 1 < NCHUNKS) produce_chunk((cc + 1) & 1, &xst[(cc + 1) & 1][0][0]);
            asm volatile("s_waitcnt vmcnt(0)" ::: "memory"); // free: issued ~5k cy ago
        } else {
            #pragma unroll 2
            for (int s = 0; s < CH; ++s) {
                // xg read: independent of h; latency hides under the FMA block
                floatx4 xg = *(const floatx4*)&ring[cc & 1][s][lane][0];

                // h broadcast: 16 same-address ds_read_b128 (conflict-free);
                // same-wave RAW after last step's h_s write (in-order DS pipe)
                const floatx4* hs4 = (const floatx4*)h_s;
                floatx4 a0, a1, a2, a3;
                {
                    floatx4 v = hs4[0];
                    a0 = w[0][0] * v; a1 = w[1][0] * v;
                    a2 = w[2][0] * v; a3 = w[3][0] * v;
                }
                #pragma unroll
                for (int q = 1; q < 16; ++q) {
                    floatx4 v = hs4[q];
                    a0 = __builtin_elementwise_fma(w[0][q], v, a0);
                    a1 = __builtin_elementwise_fma(w[1][q], v, a1);
                    a2 = __builtin_elementwise_fma(w[2][q], v, a2);
                    a3 = __builtin_elementwise_fma(w[3][q], v, a3);
                }
                floatx4 z;
                z.x = hsum4(a0); z.y = hsum4(a1);
                z.z = hsum4(a2); z.w = hsum4(a3);
                z += xg;                               // bias folded into xg

                float i_ = sigm2(z.x);
                float f_ = sigm2(z.y);
                float g_ = 2.0f * sigm2(z.z) - 1.0f;   // tanh via 2*sigma-1
                float o_ = sigm2(z.w);
                c = __builtin_fmaf(f_, c, i_ * g_);
                float th = 2.0f * sigm2(SC2 * c) - 1.0f;
                h_s[lane] = o_ * th;                   // next step's broadcast
            }
        }
    }

    // ---- epilogue: out[b] = h_T @ fc_w^T + fc_b (same-wave h_s RAW) ----
    if (wave == 0 && lane < OUTN) {
        float acc = fc_b[lane];
        #pragma unroll
        for (int j = 0; j < Hh; ++j) acc += fc_w[lane * Hh + j] * h_s[j];
        out[b * OUTN + lane] = acc;
    }
}

extern "C" void kernel_launch(void* const* d_in, const int* in_sizes, int n_in,
                              void* d_out, int out_size, void* d_ws, size_t ws_size,
                              hipStream_t stream) {
    const float* x    = (const float*)d_in[0];
    const float* w_ih = (const float*)d_in[1];
    const float* w_hh = (const float*)d_in[2];
    const float* b_ih = (const float*)d_in[3];
    const float* b_hh = (const float*)d_in[4];
    const float* fc_w = (const float*)d_in[5];
    const float* fc_b = (const float*)d_in[6];
    float* out = (float*)d_out;

    lstm_pc_kernel<<<Bb, 128, 0, stream>>>(x, w_ih, w_hh, b_ih, b_hh,
                                           fc_w, fc_b, out);
}

// Round 3
// 1966.006 us; speedup vs baseline: 1.1519x; 1.1519x over previous
//
#include <hip/hip_runtime.h>
#include <math.h>

// LSTM B=256, T=2048, D=H=64, OUT=8, fp32.
// Round-9: round-8 producer/consumer structure, minus the scratch spills.
// Round-8 post-mortem: 256 weight VGPRs + ~40 working regs > 256 architected
// VGPRs -> ~9 floatx4/thread spilled to scratch (WRITE_SIZE 8K->4.6MB), spill
// reloads on the serial recurrence path every step -> 2194 us.
// Fix: o-gate weights (16 floatx4 = 64 regs) pinned into AGPRs ("a"
// constraint; gfx950 unified file, VALU can source AGPRs / cheap accvgpr
// moves). Arch-VGPR demand ~236 < 256 -> spill-free. Consumer loop unroll 1
// to keep live ranges flat. All else identical to the round-8 kernel that
// passed (absmax 3.8e-6).
//  - Producer wave (wave 1): W_ih in regs, streams x via global_load_lds,
//    computes xg_t = scaled(W_ih x_t + b) for chunk cc+1 into ring[(cc+1)&1].
//  - Consumer wave (wave 0): W_hh in regs, walks the recurrence alone:
//    per step: h broadcast (1 ds_write + 16 same-addr ds_read_b128), 128
//    v_pk_fma_f32, hsum, pre-scaled-logit activations (exp2+rcp).
//  - One uniform __syncthreads per 16-step chunk; no spin-waits.

#define Hh 64
#define Tt 2048
#define Bb 256
#define OUTN 8
#define CH 16                 // steps per chunk (barrier granularity)
#define NCHUNKS (Tt / CH)     // 128

typedef float floatx4 __attribute__((ext_vector_type(4)));
typedef float floatx2 __attribute__((ext_vector_type(2)));

__device__ __forceinline__ float hsum4(floatx4 a) {
    floatx2 t = a.lo + a.hi;          // v_pk_add_f32
    return t.x + t.y;
}

// sigma(z) given the PRE-SCALED logit zp = -log2e * z
__device__ __forceinline__ float sigm2(float zp) {
    return __builtin_amdgcn_rcpf(1.0f + __builtin_amdgcn_exp2f(zp));
}

__global__ __launch_bounds__(128, 1)
void lstm_pc_kernel(const float* __restrict__ x,
                    const float* __restrict__ w_ih,
                    const float* __restrict__ w_hh,
                    const float* __restrict__ b_ih,
                    const float* __restrict__ b_hh,
                    const float* __restrict__ fc_w,
                    const float* __restrict__ fc_b,
                    float* __restrict__ out)
{
    __shared__ __align__(16) float ring[2][CH][Hh][4];  // 32 KB: xg double-buffer
    __shared__ __align__(16) float xst[2][CH][Hh];      // 8 KB: x staging dbuf
    __shared__ __align__(16) float h_s[Hh];             // consumer's h broadcast

    const int tid  = threadIdx.x;
    const int b    = blockIdx.x;
    const int wave = tid >> 6;     // 1 = producer, 0 = consumer
    const int lane = tid & 63;
    const float* xb = x + (size_t)b * Tt * Hh;

    const float SC1 = -1.44269504088896340736f;   // -log2(e)
    const float SC2 = -2.88539008177792681472f;   // -2*log2(e)

    // ---- per-wave weights: producer=W_ih, consumer=W_hh (pre-scaled) ----
    // gates i,f,g (192 regs) in VGPRs; gate o (64 regs) in AGPRs.
    floatx4 wv[3][16];
    floatx4 wa[16];
    {
        const float* wp = (wave == 1) ? w_ih : w_hh;
        #pragma unroll
        for (int g = 0; g < 3; ++g) {
            const float sc = (g == 2) ? SC2 : SC1;
            const floatx4* p = (const floatx4*)(wp + (size_t)((g << 6) + lane) * Hh);
            #pragma unroll
            for (int q = 0; q < 16; ++q) wv[g][q] = p[q] * sc;
        }
        const floatx4* p3 = (const floatx4*)(wp + (size_t)(192 + lane) * Hh);
        #pragma unroll
        for (int q = 0; q < 16; ++q) wa[q] = p3[q] * SC1;

        #pragma unroll
        for (int g = 0; g < 3; ++g)
            #pragma unroll
            for (int q = 0; q < 16; ++q)
                asm volatile("" : "+v"(wv[g][q]));
        #pragma unroll
        for (int q = 0; q < 16; ++q)
            asm volatile("" : "+a"(wa[q]));   // pin o-gate weights in AGPRs
    }

    floatx4 bias4;                                // consumed by producer only
    bias4.x = (b_ih[lane]       + b_hh[lane])       * SC1;   // i
    bias4.y = (b_ih[64 + lane]  + b_hh[64 + lane])  * SC1;   // f
    bias4.z = (b_ih[128 + lane] + b_hh[128 + lane]) * SC2;   // g (tanh)
    bias4.w = (b_ih[192 + lane] + b_hh[192 + lane]) * SC1;   // o

    // stage chunk -> xst[xbuf] (4 KB = 4 x 1KB wave-wide calls)
    auto stage_chunk = [&](int xbuf, int chunk) {
        const float* src = xb + (size_t)chunk * CH * Hh;
        float* dst = &xst[xbuf][0][0];
        #pragma unroll
        for (int p4 = 0; p4 < 4; ++p4)
            __builtin_amdgcn_global_load_lds(
                (const __attribute__((address_space(1))) void*)(src + p4 * 256 + lane * 4),
                (__attribute__((address_space(3))) void*)(dst + p4 * 256 + lane * 4),
                16, 0, 0);
    };

    // xg for one chunk: ring[rbuf][s][lane] = scaled(W_ih x_s + b)
    auto produce_chunk = [&](int rbuf, const float* xc) {
        #pragma unroll 1
        for (int s = 0; s < CH; ++s) {
            const floatx4* xs = (const floatx4*)(xc + s * Hh);  // broadcast reads
            floatx4 a0, a1, a2, a3;
            {
                floatx4 v = xs[0];
                a0 = wv[0][0] * v; a1 = wv[1][0] * v;
                a2 = wv[2][0] * v; a3 = wa[0] * v;
            }
            #pragma unroll
            for (int q = 1; q < 16; ++q) {
                floatx4 v = xs[q];
                a0 = __builtin_elementwise_fma(wv[0][q], v, a0);
                a1 = __builtin_elementwise_fma(wv[1][q], v, a1);
                a2 = __builtin_elementwise_fma(wv[2][q], v, a2);
                a3 = __builtin_elementwise_fma(wa[q],    v, a3);
            }
            floatx4 xg;
            xg.x = hsum4(a0); xg.y = hsum4(a1);
            xg.z = hsum4(a2); xg.w = hsum4(a3);
            xg += bias4;
            *(floatx4*)&ring[rbuf][s][lane][0] = xg;
        }
    };

    // ---- prologue: producer readies ring[0]; consumer zeroes h ----
    if (wave == 1) {
        stage_chunk(0, 0);
        stage_chunk(1, 1);
        asm volatile("s_waitcnt vmcnt(4)" ::: "memory");   // chunk 0 arrived
        __builtin_amdgcn_sched_barrier(0);
        produce_chunk(0, &xst[0][0][0]);
    } else {
        h_s[lane] = 0.0f;
    }

    float c = 0.0f;

    for (int cc = 0; cc < NCHUNKS; ++cc) {
        __syncthreads();   // ring[cc&1] ready; prior reads of ring[(cc+1)&1] retired

        if (wave == 1) {
            // stage chunk cc+2 into the xst buffer freed last iteration
            if (cc + 2 < NCHUNKS) stage_chunk(cc & 1, cc + 2);
            // chunk cc+1's x arrived (drained by last iteration's vmcnt(0))
            if (cc + 1 < NCHUNKS) produce_chunk((cc + 1) & 1, &xst[(cc + 1) & 1][0][0]);
            asm volatile("s_waitcnt vmcnt(0)" ::: "memory"); // issued ~5k cy ago
        } else {
            #pragma unroll 1
            for (int s = 0; s < CH; ++s) {
                // xg read: independent of h; latency hides under the FMA block
                floatx4 xg = *(const floatx4*)&ring[cc & 1][s][lane][0];

                // h broadcast: 16 same-address ds_read_b128 (conflict-free);
                // same-wave RAW on last step's h_s write (in-order DS pipe)
                const floatx4* hs4 = (const floatx4*)h_s;
                floatx4 a0, a1, a2, a3;
                {
                    floatx4 v = hs4[0];
                    a0 = wv[0][0] * v; a1 = wv[1][0] * v;
                    a2 = wv[2][0] * v; a3 = wa[0] * v;
                }
                #pragma unroll
                for (int q = 1; q < 16; ++q) {
                    floatx4 v = hs4[q];
                    a0 = __builtin_elementwise_fma(wv[0][q], v, a0);
                    a1 = __builtin_elementwise_fma(wv[1][q], v, a1);
                    a2 = __builtin_elementwise_fma(wv[2][q], v, a2);
                    a3 = __builtin_elementwise_fma(wa[q],    v, a3);
                }
                floatx4 z;
                z.x = hsum4(a0); z.y = hsum4(a1);
                z.z = hsum4(a2); z.w = hsum4(a3);
                z += xg;                               // bias folded into xg

                float i_ = sigm2(z.x);
                float f_ = sigm2(z.y);
                float g_ = 2.0f * sigm2(z.z) - 1.0f;   // tanh via 2*sigma-1
                float o_ = sigm2(z.w);
                c = __builtin_fmaf(f_, c, i_ * g_);
                float th = 2.0f * sigm2(SC2 * c) - 1.0f;
                h_s[lane] = o_ * th;                   // next step's broadcast
            }
        }
    }

    // ---- epilogue: out[b] = h_T @ fc_w^T + fc_b (same-wave h_s RAW) ----
    if (wave == 0 && lane < OUTN) {
        float acc = fc_b[lane];
        #pragma unroll
        for (int j = 0; j < Hh; ++j) acc += fc_w[lane * Hh + j] * h_s[j];
        out[b * OUTN + lane] = acc;
    }
}

extern "C" void kernel_launch(void* const* d_in, const int* in_sizes, int n_in,
                              void* d_out, int out_size, void* d_ws, size_t ws_size,
                              hipStream_t stream) {
    const float* x    = (const float*)d_in[0];
    const float* w_ih = (const float*)d_in[1];
    const float* w_hh = (const float*)d_in[2];
    const float* b_ih = (const float*)d_in[3];
    const float* b_hh = (const float*)d_in[4];
    const float* fc_w = (const float*)d_in[5];
    const float* fc_b = (const float*)d_in[6];
    float* out = (float*)d_out;

    lstm_pc_kernel<<<Bb, 128, 0, stream>>>(x, w_ih, w_hh, b_ih, b_hh,
                                           fc_w, fc_b, out);
}

// Round 4
// 1053.823 us; speedup vs baseline: 2.1491x; 1.8656x over previous
//
#include <hip/hip_runtime.h>
#include <math.h>

// LSTM B=256, T=2048, D=H=64, OUT=8, fp32. One block (4 waves) per batch row.
// Round-10 = round-6 (993 us, proven) + ONE change: the h broadcast between
// steps moves from LDS (ds_write h_s -> next-step 4x ds_read_b128, an
// exposed ~120-150 cy in-order DS RAW on the serial chain) to in-register
// v_readlane: after the activation every wave holds h[j] in lane j (all
// waves reduce all 4 partials redundantly), and the 16 h values wave w
// needs next step are wave-uniform -> 16 readlanes into SGPRs (~30 cy,
// no LDS). Also removes 5 DS ops/wave/step -> less barrier skew.
// Everything else (k-split, P exchange, x-dot software pipeline covering
// the P-read latency, chunk staging, packed math, pre-scaled logits) is
// byte-identical to round-6.
//
// Round-8/9 lesson (producer/consumer split): single-wave recurrence is
// issue-bound (128 pk-FMA/step) and the producer's 16 broadcast ds_reads
// per step contend on the CU's shared LDS pipe -> 2x SLOWER than the
// 4-wave k-split. Reverted to the k-split structure.

#define Hh 64
#define Tt 2048
#define Bb 256
#define OUTN 8
#define CHUNK 64
#define NCHUNK (Tt / CHUNK)

typedef float floatx4 __attribute__((ext_vector_type(4)));
typedef float floatx2 __attribute__((ext_vector_type(2)));

__device__ __forceinline__ float hsum4(floatx4 a) {
    floatx2 t = a.lo + a.hi;          // v_pk_add_f32
    return t.x + t.y;
}

// sigma(z) given the PRE-SCALED logit zp = -log2e * z
__device__ __forceinline__ float sigm2(float zp) {
    return __builtin_amdgcn_rcpf(1.0f + __builtin_amdgcn_exp2f(zp));
}

__global__ __launch_bounds__(256, 1)
void lstm_fused_kernel(const float* __restrict__ x,
                       const float* __restrict__ w_ih,
                       const float* __restrict__ w_hh,
                       const float* __restrict__ b_ih,
                       const float* __restrict__ b_hh,
                       const float* __restrict__ fc_w,
                       const float* __restrict__ fc_b,
                       float* __restrict__ out)
{
    __shared__ __align__(16) float xch[2][CHUNK * Hh];   // 2 x 16 KB x chunks
    __shared__ __align__(16) float P[2][4][Hh][4];       // parity x wave x j x gate
    __shared__ __align__(16) float h_s[Hh];              // epilogue only

    const int tid  = threadIdx.x;
    const int b    = blockIdx.x;
    const int wave = tid >> 6;     // k-slice index
    const int lane = tid & 63;     // hidden unit j

    const float* xb = x + (size_t)b * Tt * Hh;

    const float SC1 = -1.44269504088896340736f;   // -log2(e)
    const float SC2 = -2.88539008177792681472f;   // -2*log2(e)

    // ---- weights: lane j, gate g -> row 64g+j, cols [16w,16w+16), scaled ----
    floatx4 wx[4][4], wh[4][4];    // 32 float4 = 128 regs, pinned
    {
        const int kb = 16 * wave;
        #pragma unroll
        for (int g = 0; g < 4; ++g) {
            const float sc = (g == 2) ? SC2 : SC1;
            const floatx4* pi = (const floatx4*)(w_ih + (size_t)((g << 6) + lane) * Hh + kb);
            const floatx4* ph = (const floatx4*)(w_hh + (size_t)((g << 6) + lane) * Hh + kb);
            #pragma unroll
            for (int q = 0; q < 4; ++q) { wx[g][q] = pi[q] * sc; wh[g][q] = ph[q] * sc; }
        }
        #pragma unroll
        for (int g = 0; g < 4; ++g)
            #pragma unroll
            for (int q = 0; q < 4; ++q)
                asm volatile("" : "+v"(wx[g][q]), "+v"(wh[g][q]));
    }
    floatx4 bias4;
    bias4.x = (b_ih[lane]       + b_hh[lane])       * SC1;   // i
    bias4.y = (b_ih[64 + lane]  + b_hh[64 + lane])  * SC1;   // f
    bias4.z = (b_ih[128 + lane] + b_hh[128 + lane]) * SC2;   // g (tanh)
    bias4.w = (b_ih[192 + lane] + b_hh[192 + lane]) * SC1;   // o

    // ---- stage chunk 0 (async; drained by init barrier) ----
    #pragma unroll
    for (int p4 = 0; p4 < 4; ++p4) {
        __builtin_amdgcn_global_load_lds(
            (const __attribute__((address_space(1))) void*)(xb + p4 * 1024 + tid * 4),
            (__attribute__((address_space(3))) void*)(&xch[0][p4 * 1024 + tid * 4]),
            16, 0, 0);
    }
    float c = 0.0f;                // lane j of every wave: c[j] (replicated)
    float hj = 0.0f;               // h[j] for j = lane (replicated per wave)
    // hv[q]: h values for this wave's k-slice, refreshed by readlane each step
    floatx4 hv[4];
    #pragma unroll
    for (int q = 0; q < 4; ++q) hv[q] = (floatx4)(0.0f);    // h_0 = 0
    const int kb16 = 16 * wave;
    __syncthreads();

    // ---- prime the pipeline: x-dot for (cc=0, s=0) ----
    floatx4 acc0, acc1, acc2, acc3;
    {
        const floatx4* xs = (const floatx4*)(&xch[0][16 * wave]);
        floatx4 v = xs[0];
        acc0 = wx[0][0] * v; acc1 = wx[1][0] * v;
        acc2 = wx[2][0] * v; acc3 = wx[3][0] * v;
        #pragma unroll
        for (int q = 1; q < 4; ++q) {
            v = xs[q];
            acc0 = __builtin_elementwise_fma(wx[0][q], v, acc0);
            acc1 = __builtin_elementwise_fma(wx[1][q], v, acc1);
            acc2 = __builtin_elementwise_fma(wx[2][q], v, acc2);
            acc3 = __builtin_elementwise_fma(wx[3][q], v, acc3);
        }
    }

    for (int cc = 0; cc < NCHUNK; ++cc) {
        const float* xcbuf = &xch[cc & 1][0];

        #pragma unroll 2
        for (int s = 0; s < CHUNK; ++s) {
            const int par = s & 1;

            // ---- h-half on the carried accumulators (hv from readlanes) ----
            #pragma unroll
            for (int q = 0; q < 4; ++q) {
                floatx4 v = hv[q];
                acc0 = __builtin_elementwise_fma(wh[0][q], v, acc0);
                acc1 = __builtin_elementwise_fma(wh[1][q], v, acc1);
                acc2 = __builtin_elementwise_fma(wh[2][q], v, acc2);
                acc3 = __builtin_elementwise_fma(wh[3][q], v, acc3);
            }
            floatx4 part;
            part.x = hsum4(acc0); part.y = hsum4(acc1);
            part.z = hsum4(acc2); part.w = hsum4(acc3);
            *(floatx4*)&P[par][wave][lane][0] = part;
            __syncthreads();                 // THE one barrier per step

            // stage next chunk just AFTER the s==0 barrier: its vmcnt drain
            // (next barrier) is a full step away; consumed at s==63.
            if (s == 0 && cc + 1 < NCHUNK) {
                const float* src = xb + (size_t)(cc + 1) * CHUNK * Hh;
                float* dst = &xch[(cc + 1) & 1][0];
                #pragma unroll
                for (int p4 = 0; p4 < 4; ++p4) {
                    __builtin_amdgcn_global_load_lds(
                        (const __attribute__((address_space(1))) void*)(src + p4 * 1024 + tid * 4),
                        (__attribute__((address_space(3))) void*)(dst + p4 * 1024 + tid * 4),
                        16, 0, 0);
                }
            }

            // ---- P-reads; their latency is covered by next-step x-dot ----
            floatx4 p0 = *(const floatx4*)&P[par][0][lane][0];
            floatx4 p1 = *(const floatx4*)&P[par][1][lane][0];
            floatx4 p2 = *(const floatx4*)&P[par][2][lane][0];
            floatx4 p3 = *(const floatx4*)&P[par][3][lane][0];

            // next-step x-dot (independent of P). Last step of last chunk
            // reads a stale buffer: in-bounds, result discarded.
            const float* xn = (s + 1 < CHUNK) ? (xcbuf + (s + 1) * Hh)
                                              : &xch[(cc + 1) & 1][0];
            const floatx4* xs = (const floatx4*)(xn + 16 * wave);
            floatx4 n0, n1, n2, n3;
            {
                floatx4 v = xs[0];
                n0 = wx[0][0] * v; n1 = wx[1][0] * v;
                n2 = wx[2][0] * v; n3 = wx[3][0] * v;
            }
            #pragma unroll
            for (int q = 1; q < 4; ++q) {
                floatx4 v = xs[q];
                n0 = __builtin_elementwise_fma(wx[0][q], v, n0);
                n1 = __builtin_elementwise_fma(wx[1][q], v, n1);
                n2 = __builtin_elementwise_fma(wx[2][q], v, n2);
                n3 = __builtin_elementwise_fma(wx[3][q], v, n3);
            }

            // ---- reduce + activations (pre-scaled logits) + c/h update ----
            floatx4 z = bias4 + ((p0 + p1) + (p2 + p3));
            float i_ = sigm2(z.x);
            float f_ = sigm2(z.y);
            float g_ = 2.0f * sigm2(z.z) - 1.0f;      // tanh via 2*sigma-1
            float o_ = sigm2(z.w);
            c = __builtin_fmaf(f_, c, i_ * g_);
            float th = 2.0f * sigm2(SC2 * c) - 1.0f;
            hj = o_ * th;                             // h[j], j = lane

            // ---- h broadcast via readlane (wave-uniform indices, no LDS):
            // next step this wave needs h[16w .. 16w+16)
            {
                const int hbits = __float_as_int(hj);
                #pragma unroll
                for (int q = 0; q < 4; ++q) {
                    #pragma unroll
                    for (int e = 0; e < 4; ++e) {
                        hv[q][e] = __int_as_float(
                            __builtin_amdgcn_readlane(hbits, kb16 + 4 * q + e));
                    }
                }
            }

            acc0 = n0; acc1 = n1; acc2 = n2; acc3 = n3;
        }
    }

    // ---- epilogue: out[b] = h_T @ fc_w^T + fc_b ----
    if (wave == 0) h_s[lane] = hj;      // same-wave readers below (in-order DS)
    __syncthreads();
    if (tid < OUTN) {
        float acc = fc_b[tid];
        #pragma unroll
        for (int j = 0; j < Hh; ++j) acc += fc_w[tid * Hh + j] * h_s[j];
        out[b * OUTN + tid] = acc;
    }
}

extern "C" void kernel_launch(void* const* d_in, const int* in_sizes, int n_in,
                              void* d_out, int out_size, void* d_ws, size_t ws_size,
                              hipStream_t stream) {
    const float* x    = (const float*)d_in[0];
    const float* w_ih = (const float*)d_in[1];
    const float* w_hh = (const float*)d_in[2];
    const float* b_ih = (const float*)d_in[3];
    const float* b_hh = (const float*)d_in[4];
    const float* fc_w = (const float*)d_in[5];
    const float* fc_b = (const float*)d_in[6];
    float* out = (float*)d_out;

    lstm_fused_kernel<<<Bb, 256, 0, stream>>>(x, w_ih, w_hh, b_ih, b_hh,
                                              fc_w, fc_b, out);
}